// Round 1
// baseline (20923.221 us; speedup 1.0000x reference)
//
#include <hip/hip_runtime.h>
#include <math.h>

#define NU 512     // hidden units
#define BT 128     // batch
#define TT 1024    // timesteps
#define ID 128     // input dim
#define OC 10      // out classes
#define GGRP 16    // row groups
#define CWG 16     // WGs per group (col slices)
#define RROW 8     // rows per group  (GGRP*RROW = 128)
#define JCOL 32    // cols per WG     (CWG*JCOL = 512)
#define THREADS 512

static constexpr float F_EPS = 0.01f;
static constexpr float F_CT  = 1.0f - 2.0f * 0.8f;  // coefficient of B^T = -0.6
static constexpr float F_GAM = 0.01f;

// ws layout (floats):
//   h0:  [0, 65536)            (128*512)
//   h1:  [65536, 131072)
//   cnt: ints at [131072, 131072+16384)   (GGRP * TT barrier counters)
#define WS_H1   65536
#define WS_CNT  131072

// LDS: As[512][32] + Ws[512][32] + hs[8][512] + xs[8][128] + red[256][2]
#define LDS_FLOATS (NU*JCOL + NU*JCOL + RROW*NU + RROW*ID + 256*2)
#define LDS_BYTES  (LDS_FLOATS * 4)     // 153600

__global__ void init_kernel(float* ws) {
    int i = blockIdx.x * 256 + threadIdx.x;
    if (i < BT * NU) ws[i] = 0.0f;            // zero h0
    int* cnt = (int*)(ws + WS_CNT);
    if (i < GGRP * TT) cnt[i] = 0;            // zero barrier counters
}

__global__ __launch_bounds__(THREADS, 1)
void scan_kernel(const float* __restrict__ x, const float* __restrict__ B,
                 const float* __restrict__ C, const float* __restrict__ Ew,
                 const float* __restrict__ Eb, float* ws)
{
    extern __shared__ float smem[];
    float* As  = smem;                 // [512][32]
    float* Wsm = As + NU * JCOL;       // [512][32]
    float* hs  = Wsm + NU * JCOL;      // [8][512]
    float* xs  = hs + RROW * NU;       // [8][128]
    float* red = xs + RROW * ID;       // [256][2]

    const int tid = threadIdx.x;
    const int bid = blockIdx.x;
    const int g = bid & (GGRP - 1);    // group: bid%16 -> same XCD heuristic
    const int cslice = bid >> 4;       // col slice 0..15
    const int jbase = cslice * JCOL;
    const int row0 = g * RROW;

    float* h0 = ws;
    float* h1 = ws + WS_H1;
    int* cnt = (int*)(ws + WS_CNT);

    // ---- Build A/W slices into LDS (once) ----
    // A = B + CT*B^T - GAM*I ; W likewise from C. Stored As[k][jl], jl in slice.
    // pass1: transpose term (coalesced reads of B rows jbase..jbase+31)
    {
        int k = tid;  // 512 threads == 512 k
        for (int jl = 0; jl < JCOL; ++jl) {
            int col = jbase + jl;
            As [k * JCOL + jl] = F_CT * B[(size_t)col * NU + k];
            Wsm[k * JCOL + jl] = F_CT * C[(size_t)col * NU + k];
        }
    }
    __syncthreads();
    // pass2: += B[k][col] - gamma on diag (coalesced across jl)
    {
        int jl = tid & 31;
        int kb = tid >> 5;   // 0..15
        int col = jbase + jl;
        for (int kk = 0; kk < NU; kk += 16) {
            int k = kb + kk;
            float dia = (k == col) ? F_GAM : 0.0f;
            As [k * JCOL + jl] += B[(size_t)k * NU + col] - dia;
            Wsm[k * JCOL + jl] += C[(size_t)k * NU + col] - dia;
        }
    }
    __syncthreads();

    // ---- per-thread compute mapping ----
    const int kc  = tid >> 8;          // 0,1 : k half
    const int rem = tid & 255;
    const int r   = rem >> 5;          // 0..7 row in group
    const int j   = rem & 31;          // col in slice
    const int col = jbase + j;
    const float ebv = Eb[col];
    const int koff = kc * 256;

    for (int t = 0; t < TT; ++t) {
        const float* hin  = (t & 1) ? h1 : h0;
        float*       hout = (t & 1) ? h0 : h1;

        // stage full group h (16KB) via agent-scope loads (cross-XCD fresh)
        {
            int base = tid * 8;
            int rr = base >> 9;
            int cc = base & (NU - 1);
            const float* src = hin + (size_t)(row0 + rr) * NU + cc;
            float* dst = hs + base;
            #pragma unroll
            for (int u = 0; u < 8; ++u)
                dst[u] = __hip_atomic_load(src + u, __ATOMIC_RELAXED,
                                           __HIP_MEMORY_SCOPE_AGENT);
        }
        // stage x_t rows (plain cached loads, read-only input)
        {
            int base = tid * 2;
            int rr = base >> 7;
            int ii = base & (ID - 1);
            const float* src = x + (size_t)(row0 + rr) * TT * ID + (size_t)t * ID + ii;
            xs[base]     = src[0];
            xs[base + 1] = src[1];
        }
        __syncthreads();

        float acc_a = 0.0f, acc_w = 0.0f;
        {
            const float* hrow = hs + r * NU + koff;
            const float* Ap = As  + (size_t)koff * JCOL + j;
            const float* Wp = Wsm + (size_t)koff * JCOL + j;
            #pragma unroll 4
            for (int k4 = 0; k4 < 64; ++k4) {
                float4 hv = *(const float4*)(hrow + k4 * 4);
                int kb = k4 * 4 * JCOL;
                acc_a += hv.x * Ap[kb];
                acc_w += hv.x * Wp[kb];
                acc_a += hv.y * Ap[kb + JCOL];
                acc_w += hv.y * Wp[kb + JCOL];
                acc_a += hv.z * Ap[kb + 2 * JCOL];
                acc_w += hv.z * Wp[kb + 2 * JCOL];
                acc_a += hv.w * Ap[kb + 3 * JCOL];
                acc_w += hv.w * Wp[kb + 3 * JCOL];
            }
        }
        // z partial: this thread's i-half of x_t @ E_w (E_w slice stays L1-hot)
        {
            const float* xr = xs + r * ID + kc * 64;
            const float* Ep = Ew + (size_t)(kc * 64) * NU + col;
            #pragma unroll 4
            for (int i = 0; i < 64; ++i)
                acc_w += xr[i] * Ep[(size_t)i * NU];
        }

        if (kc == 1) { red[rem * 2] = acc_a; red[rem * 2 + 1] = acc_w; }
        __syncthreads();
        if (kc == 0) {
            acc_a += red[rem * 2];
            acc_w += red[rem * 2 + 1] + ebv;
            float hv = hs[r * NU + col];
            float hnew = hv + F_EPS * acc_a + F_EPS * tanhf(acc_w);
            __hip_atomic_store(hout + (size_t)(row0 + r) * NU + col, hnew,
                               __ATOMIC_RELAXED, __HIP_MEMORY_SCOPE_AGENT);
        }
        __syncthreads();   // drains vmcnt: all our stores complete before arrival
        if (tid == 0) {
            __hip_atomic_fetch_add(&cnt[g * TT + t], 1, __ATOMIC_RELEASE,
                                   __HIP_MEMORY_SCOPE_AGENT);
            while (__hip_atomic_load(&cnt[g * TT + t], __ATOMIC_ACQUIRE,
                                     __HIP_MEMORY_SCOPE_AGENT) < CWG)
                __builtin_amdgcn_s_sleep(1);
        }
        __syncthreads();
    }
}

__global__ void head_kernel(const float* __restrict__ ws, const float* __restrict__ Dw,
                            const float* __restrict__ Db, float* __restrict__ out)
{
    __shared__ float red2[32][16];
    int b = blockIdx.x;
    int tid = threadIdx.x;        // 512
    int j = tid & 15;
    int kc = tid >> 4;            // 0..31, 16 k each
    const float* h = ws + (size_t)b * NU;   // final h lives in h0
    float acc = 0.0f;
    if (j < OC) {
        for (int u = 0; u < 16; ++u) {
            int k = kc * 16 + u;
            acc += h[k] * Dw[(size_t)k * OC + j];
        }
    }
    red2[kc][j] = acc;
    __syncthreads();
    if (kc == 0 && j < OC) {
        float s = 0.0f;
        #pragma unroll
        for (int u = 0; u < 32; ++u) s += red2[u][j];
        out[(size_t)b * OC + j] = s + Db[j];
    }
}

extern "C" void kernel_launch(void* const* d_in, const int* in_sizes, int n_in,
                              void* d_out, int out_size, void* d_ws, size_t ws_size,
                              hipStream_t stream) {
    const float* x  = (const float*)d_in[0];
    const float* B  = (const float*)d_in[1];
    const float* C  = (const float*)d_in[2];
    const float* Ew = (const float*)d_in[3];
    const float* Eb = (const float*)d_in[4];
    const float* Dw = (const float*)d_in[5];
    const float* Db = (const float*)d_in[6];
    float* ws  = (float*)d_ws;
    float* out = (float*)d_out;

    // dynamic LDS 150 KB > 64 KB default: opt in every call (capture-safe, no-op after first)
    (void)hipFuncSetAttribute((const void*)scan_kernel,
                              hipFuncAttributeMaxDynamicSharedMemorySize, LDS_BYTES);

    init_kernel<<<256, 256, 0, stream>>>(ws);
    scan_kernel<<<GGRP * CWG, THREADS, LDS_BYTES, stream>>>(x, B, C, Ew, Eb, ws);
    head_kernel<<<BT, THREADS, 0, stream>>>(ws, Dw, Db, out);
}

// Round 3
// 6306.804 us; speedup vs baseline: 3.3176x; 3.3176x over previous
//
#include <hip/hip_runtime.h>
#include <math.h>

#define NU 512     // hidden units
#define BT 128     // batch
#define TT 1024    // timesteps
#define ID 128     // input dim
#define OC 10      // out classes
#define GGRP 32    // row groups
#define CWG 8      // WGs per group (col slices)
#define RROW 4     // rows per group   (GGRP*RROW = 128)
#define JCOL 64    // cols per WG      (CWG*JCOL = 512)
#define THREADS 512

static constexpr float F_EPS = 0.01f;
static constexpr float F_CT  = -0.6f;   // coefficient of B^T / C^T (beta=0.8)
static constexpr float F_GAM = 0.01f;

// ws layout (floats): h0 [0,65536) | h1 [65536,131072) | cnt ints [131072,+32768)
#define WS_H1  65536
#define WS_CNT 131072

// LDS (dwords): hs[4][544] skewed fp32 h rows, xs[4][160] skewed x rows.
// Skew: logical (r,k) -> r*544 + k + (k>>6)*4   (k-block of 64 shifts 4 dwords
//       so the 8 kc lanes start on 8 distinct 4-bank groups)
//       logical (r,i) -> r*160 + i + (i>>4)*4   (i-block of 16, same idea)
#define OFF_H 0
#define OFF_X 2176
#define LDS_DW 2816
// Pad dynamic LDS to 96 KB: forces exactly 1 WG/CU (160 KB pool) so all 256
// WGs are co-resident -> the inter-WG spin barrier cannot deadlock.
#define LDS_BYTES 98304

typedef float f32x4 __attribute__((ext_vector_type(4)));

__global__ void init_kernel(float* ws) {
    int i = blockIdx.x * 256 + threadIdx.x;   // 65536 threads
    if (i < BT * NU) ws[i] = 0.0f;            // zero h0
    int* cnt = (int*)(ws + WS_CNT);
    if (i < GGRP * TT) cnt[i] = 0;            // zero barrier counters
}

__global__ __launch_bounds__(THREADS, 2)
void scan_kernel(const float* __restrict__ x, const float* __restrict__ B,
                 const float* __restrict__ C, const float* __restrict__ Ew,
                 const float* __restrict__ Eb, float* ws)
{
    extern __shared__ float sm[];
    const int tid = threadIdx.x;
    const int bid = blockIdx.x;
    const int g = bid & (GGRP - 1);   // group; members share bid%8 -> same XCD
    const int slice = bid >> 5;       // col slice 0..7
    const int jbase = slice * JCOL;
    const int row0 = g * RROW;

    float* h0 = ws;
    float* h1 = ws + WS_H1;
    int* cntg = (int*)(ws + WS_CNT) + g * TT;

    // compute mapping: wave w -> 8 cols; lane = kc*8 + jl; kc = 8-way k split
    const int lane = tid & 63;
    const int w = tid >> 6;
    const int jl = lane & 7;
    const int kc = lane >> 3;
    const int cg = jbase + w * 8 + jl;     // this thread's global column
    const int k0 = kc * 64;                // this thread's k range [k0, k0+64)

    // ---- register-resident weights (constant across all 1024 steps) ----
    float regA[64], regW[64], regE[16];
    #pragma unroll
    for (int u = 0; u < 64; ++u) {
        int k = k0 + u;
        float dia = (k == cg) ? F_GAM : 0.0f;
        regA[u] = B[(size_t)k * NU + cg] + F_CT * B[(size_t)cg * NU + k] - dia;
        regW[u] = C[(size_t)k * NU + cg] + F_CT * C[(size_t)cg * NU + k] - dia;
    }
    #pragma unroll
    for (int v = 0; v < 16; ++v)
        regE[v] = Ew[(size_t)(kc * 16 + v) * NU + cg];
    const float ebv = Eb[cg];

    // staging mapping: each thread stages 16B of h and 4B of x
    const int sr = tid >> 7;               // row 0..3
    const int sk = (tid & 127) * 4;        // h dword base
    const int xi = tid & 127;              // x element
    const int hp = sr * 544 + sk + (sk >> 6) * 4;
    const int xp = sr * 160 + xi + (xi >> 4) * 4;
    const size_t xrow = (size_t)(row0 + sr) * TT * ID;

    for (int t = 0; t < TT; ++t) {
        const float* hin = (t & 1) ? h1 : h0;
        float* hout = (t & 1) ? h0 : h1;

        // stage group h rows: 4 coherent dword loads -> one b128 LDS write
        {
            const float* src = hin + (size_t)(row0 + sr) * NU + sk;
            f32x4 v;
            #pragma unroll
            for (int u = 0; u < 4; ++u)
                v[u] = __hip_atomic_load(src + u, __ATOMIC_RELAXED,
                                         __HIP_MEMORY_SCOPE_AGENT);
            *(f32x4*)(sm + OFF_H + hp) = v;
            sm[OFF_X + xp] = x[xrow + (size_t)t * ID + xi];  // plain cached
        }
        __syncthreads();

        float accA[RROW] = {0.f, 0.f, 0.f, 0.f};
        float accW[RROW] = {0.f, 0.f, 0.f, 0.f};

        // h @ A and h @ W partials over this thread's 64 k (weights in VGPRs)
        #pragma unroll
        for (int r = 0; r < RROW; ++r) {
            const float* hr = sm + OFF_H + r * 544 + kc * 68;
            #pragma unroll
            for (int q = 0; q < 16; ++q) {
                f32x4 hv = *(const f32x4*)(hr + q * 4);
                #pragma unroll
                for (int s = 0; s < 4; ++s) {
                    accA[r] = fmaf(hv[s], regA[q * 4 + s], accA[r]);
                    accW[r] = fmaf(hv[s], regW[q * 4 + s], accW[r]);
                }
            }
        }
        // z partial: x_t @ Ew over this thread's 16 i
        #pragma unroll
        for (int r = 0; r < RROW; ++r) {
            const float* xr = sm + OFF_X + r * 160 + kc * 20;
            #pragma unroll
            for (int q = 0; q < 4; ++q) {
                f32x4 xv = *(const f32x4*)(xr + q * 4);
                #pragma unroll
                for (int s = 0; s < 4; ++s)
                    accW[r] = fmaf(xv[s], regE[q * 4 + s], accW[r]);
            }
        }
        // reduce over kc (lane bits 3..5)
        #pragma unroll
        for (int m = 8; m <= 32; m <<= 1) {
            #pragma unroll
            for (int r = 0; r < RROW; ++r) {
                accA[r] += __shfl_xor(accA[r], m, 64);
                accW[r] += __shfl_xor(accW[r], m, 64);
            }
        }
        // owners (kc==0): exact fp32 state update + coherent store
        if (kc == 0) {
            #pragma unroll
            for (int r = 0; r < RROW; ++r) {
                float hold = sm[OFF_H + r * 544 + cg + (cg >> 6) * 4];
                float hnew = hold + F_EPS * accA[r]
                           + F_EPS * tanhf(accW[r] + ebv);
                __hip_atomic_store(hout + (size_t)(row0 + r) * NU + cg, hnew,
                                   __ATOMIC_RELAXED, __HIP_MEMORY_SCOPE_AGENT);
            }
        }
        __syncthreads();   // all lanes done with sm; drains vmcnt (stores out)
        if (tid == 0 && t < TT - 1) {
            __hip_atomic_fetch_add(cntg + t, 1, __ATOMIC_RELEASE,
                                   __HIP_MEMORY_SCOPE_AGENT);
            while (__hip_atomic_load(cntg + t, __ATOMIC_RELAXED,
                                     __HIP_MEMORY_SCOPE_AGENT) < CWG)
                __builtin_amdgcn_s_sleep(2);
        }
        __syncthreads();
    }
}

__global__ void head_kernel(const float* __restrict__ ws, const float* __restrict__ Dw,
                            const float* __restrict__ Db, float* __restrict__ out)
{
    __shared__ float red2[32][16];
    int b = blockIdx.x;
    int tid = threadIdx.x;        // 512
    int j = tid & 15;
    int kc = tid >> 4;            // 0..31, 16 k each
    const float* h = ws + (size_t)b * NU;   // final h lives in h0 (TT even)
    float acc = 0.0f;
    if (j < OC) {
        for (int u = 0; u < 16; ++u) {
            int k = kc * 16 + u;
            acc += h[k] * Dw[(size_t)k * OC + j];
        }
    }
    red2[kc][j] = acc;
    __syncthreads();
    if (kc == 0 && j < OC) {
        float s = 0.0f;
        #pragma unroll
        for (int u = 0; u < 32; ++u) s += red2[u][j];
        out[(size_t)b * OC + j] = s + Db[j];
    }
}

extern "C" void kernel_launch(void* const* d_in, const int* in_sizes, int n_in,
                              void* d_out, int out_size, void* d_ws, size_t ws_size,
                              hipStream_t stream) {
    const float* x  = (const float*)d_in[0];
    const float* B  = (const float*)d_in[1];
    const float* C  = (const float*)d_in[2];
    const float* Ew = (const float*)d_in[3];
    const float* Eb = (const float*)d_in[4];
    const float* Dw = (const float*)d_in[5];
    const float* Db = (const float*)d_in[6];
    float* ws  = (float*)d_ws;
    float* out = (float*)d_out;

    (void)hipFuncSetAttribute((const void*)scan_kernel,
                              hipFuncAttributeMaxDynamicSharedMemorySize, LDS_BYTES);

    init_kernel<<<256, 256, 0, stream>>>(ws);
    scan_kernel<<<GGRP * CWG, THREADS, LDS_BYTES, stream>>>(x, B, C, Ew, Eb, ws);
    head_kernel<<<BT, THREADS, 0, stream>>>(ws, Dw, Db, out);
}

// Round 4
// 5405.698 us; speedup vs baseline: 3.8706x; 1.1667x over previous
//
#include <hip/hip_runtime.h>
#include <math.h>

#define NU 512     // hidden units
#define BT 128     // batch
#define TT 1024    // timesteps
#define ID 128     // input dim
#define OC 10      // out classes
#define GGRP 32    // row groups
#define CWG 8      // WGs per group (col slices)
#define RROW 4     // rows per group   (GGRP*RROW = 128)
#define JCOL 64    // cols per WG      (CWG*JCOL = 512)
#define THREADS 512

static constexpr float F_EPS = 0.01f;
static constexpr float F_CT  = -0.6f;   // coefficient of B^T / C^T (beta=0.8)
static constexpr float F_GAM = 0.01f;

// ws layout (floats): h0 [0,65536) | h1 [65536,131072) | cnt ints [131072,+32768)
#define WS_H1  65536
#define WS_CNT 131072

// LDS (dwords): hs[4][544] skewed fp32 h rows; xs double buffer 2 x [4][160].
// Skew: (r,k) -> r*544 + k + (k>>6)*4 ; (r,i) -> r*160 + i + (i>>4)*4
#define OFF_H  0
#define OFF_X0 2176
#define OFF_X1 2816
// Pad dynamic LDS to 96 KB: forces exactly 1 WG/CU so all 256 WGs are
// co-resident -> the inter-WG spin barrier cannot deadlock.
#define LDS_BYTES 98304

typedef float f32x4 __attribute__((ext_vector_type(4)));
typedef float f32x2 __attribute__((ext_vector_type(2)));

__global__ void init_kernel(float* ws) {
    int i = blockIdx.x * 256 + threadIdx.x;   // 65536 threads
    if (i < BT * NU) ws[i] = 0.0f;            // zero h0
    int* cnt = (int*)(ws + WS_CNT);
    if (i < GGRP * TT) cnt[i] = 0;            // zero barrier counters
}

__global__ __launch_bounds__(THREADS, 2)
void scan_kernel(const float* __restrict__ x, const float* __restrict__ B,
                 const float* __restrict__ C, const float* __restrict__ Ew,
                 const float* __restrict__ Eb, float* ws)
{
    extern __shared__ float sm[];
    const int tid = threadIdx.x;
    const int bid = blockIdx.x;
    const int g = bid & (GGRP - 1);   // group; members share bid%8 -> same XCD
    const int slice = bid >> 5;       // col slice 0..7
    const int jbase = slice * JCOL;
    const int row0 = g * RROW;

    float* h0 = ws;
    float* h1 = ws + WS_H1;
    int* cntg = (int*)(ws + WS_CNT) + g * TT;

    // compute mapping: wave w -> 8 cols; lane = kc*8 + jl; kc = 8-way k split
    const int lane = tid & 63;
    const int w = tid >> 6;
    const int jl = lane & 7;
    const int kc = lane >> 3;
    const int cg = jbase + w * 8 + jl;     // this thread's global column
    const int k0 = kc * 64;                // this thread's k range [k0, k0+64)

    // ---- register-resident weights (constant across all 1024 steps) ----
    f32x2 rA[32], rW[32], rE[8];
    #pragma unroll
    for (int u2 = 0; u2 < 32; ++u2) {
        #pragma unroll
        for (int p = 0; p < 2; ++p) {
            int k = k0 + 2 * u2 + p;
            float dia = (k == cg) ? F_GAM : 0.0f;
            rA[u2][p] = B[(size_t)k * NU + cg] + F_CT * B[(size_t)cg * NU + k] - dia;
            rW[u2][p] = C[(size_t)k * NU + cg] + F_CT * C[(size_t)cg * NU + k] - dia;
        }
    }
    #pragma unroll
    for (int v2 = 0; v2 < 8; ++v2) {
        rE[v2][0] = Ew[(size_t)(kc * 16 + 2 * v2) * NU + cg];
        rE[v2][1] = Ew[(size_t)(kc * 16 + 2 * v2 + 1) * NU + cg];
    }
    const float ebv = Eb[cg];

    // staging mapping: each thread stages 16B of h and 4B of x
    const int sr = tid >> 7;               // row 0..3
    const int sk = (tid & 127) * 4;        // h dword base
    const int xi = tid & 127;              // x element
    const int hp = sr * 544 + sk + (sk >> 6) * 4;
    const int xp = sr * 160 + xi + (xi >> 4) * 4;
    const size_t xrow = (size_t)(row0 + sr) * TT * ID;

    // stage x for t=0
    sm[OFF_X0 + xp] = x[xrow + xi];
    __syncthreads();

    for (int t = 0; t < TT; ++t) {
        const float* hin = (t & 1) ? h1 : h0;
        float* hout = (t & 1) ? h0 : h1;
        const int xcur = (t & 1) ? OFF_X1 : OFF_X0;
        const int xnxt = (t & 1) ? OFF_X0 : OFF_X1;

        // 1. issue coherent h load (16B, LLC-fresh), do NOT wait yet
        f32x4 hvv;
        {
            const float* src = hin + (size_t)(row0 + sr) * NU + sk;
            asm volatile("global_load_dwordx4 %0, %1, off sc0 sc1"
                         : "=v"(hvv) : "v"(src));
        }

        // 2. z partials from xcur (staged last iter) — overlaps h-load latency
        f32x2 zac[RROW];
        #pragma unroll
        for (int r = 0; r < RROW; ++r) {
            zac[r] = (f32x2){0.f, 0.f};
            const float* xr = sm + xcur + r * 160 + kc * 20;
            #pragma unroll
            for (int q = 0; q < 4; ++q) {
                f32x4 xv = *(const f32x4*)(xr + q * 4);
                f32x2 xlo = __builtin_shufflevector(xv, xv, 0, 1);
                f32x2 xhi = __builtin_shufflevector(xv, xv, 2, 3);
                zac[r] = __builtin_elementwise_fma(xlo, rE[2 * q], zac[r]);
                zac[r] = __builtin_elementwise_fma(xhi, rE[2 * q + 1], zac[r]);
            }
        }

        // 3. wait for h, publish to LDS
        asm volatile("s_waitcnt vmcnt(0)" : "+v"(hvv) :: "memory");
        *(f32x4*)(sm + OFF_H + hp) = hvv;
        __syncthreads();

        // 4. h @ A and h @ W partials over this thread's 64 k (weights in VGPRs)
        f32x2 aA[RROW], aW[RROW];
        #pragma unroll
        for (int r = 0; r < RROW; ++r) {
            aA[r] = (f32x2){0.f, 0.f};
            aW[r] = zac[r];
            const float* hr = sm + OFF_H + r * 544 + kc * 68;
            #pragma unroll
            for (int q = 0; q < 16; ++q) {
                f32x4 hv = *(const f32x4*)(hr + q * 4);
                f32x2 hlo = __builtin_shufflevector(hv, hv, 0, 1);
                f32x2 hhi = __builtin_shufflevector(hv, hv, 2, 3);
                aA[r] = __builtin_elementwise_fma(hlo, rA[2 * q], aA[r]);
                aW[r] = __builtin_elementwise_fma(hlo, rW[2 * q], aW[r]);
                aA[r] = __builtin_elementwise_fma(hhi, rA[2 * q + 1], aA[r]);
                aW[r] = __builtin_elementwise_fma(hhi, rW[2 * q + 1], aW[r]);
            }
        }

        // 5. collapse f32x2 -> scalar, butterfly over kc (lane bits 3..5)
        float sA[RROW], sW[RROW];
        #pragma unroll
        for (int r = 0; r < RROW; ++r) {
            sA[r] = aA[r][0] + aA[r][1];
            sW[r] = aW[r][0] + aW[r][1];
        }
        #pragma unroll
        for (int m = 8; m <= 32; m <<= 1) {
            #pragma unroll
            for (int r = 0; r < RROW; ++r) {
                sA[r] += __shfl_xor(sA[r], m, 64);
                sW[r] += __shfl_xor(sW[r], m, 64);
            }
        }

        // 6. every lane has all 4 row sums; lane-group kc==r owns row r
        //    (one tanh eval at 32/64 active lanes, one store instr)
        if (kc < RROW) {
            int r = kc;
            float hold = sm[OFF_H + r * 544 + cg + (cg >> 6) * 4];
            float hnew = hold + F_EPS * sA[r] + F_EPS * tanhf(sW[r] + ebv);
            __hip_atomic_store(hout + (size_t)(row0 + r) * NU + cg, hnew,
                               __ATOMIC_RELAXED, __HIP_MEMORY_SCOPE_AGENT);
        }

        // 7. stage x for t+1 (overlaps store drain / spin window)
        if (t + 1 < TT)
            sm[xnxt + xp] = x[xrow + (size_t)(t + 1) * ID + xi];

        __syncthreads();   // all waves drain vmcnt (h stores globally visible)
        if (tid == 0 && t < TT - 1) {
            __hip_atomic_fetch_add(cntg + t, 1, __ATOMIC_RELEASE,
                                   __HIP_MEMORY_SCOPE_AGENT);
            while (__hip_atomic_load(cntg + t, __ATOMIC_RELAXED,
                                     __HIP_MEMORY_SCOPE_AGENT) < CWG)
                __builtin_amdgcn_s_sleep(1);
        }
        __syncthreads();
    }
}

__global__ void head_kernel(const float* __restrict__ ws, const float* __restrict__ Dw,
                            const float* __restrict__ Db, float* __restrict__ out)
{
    __shared__ float red2[32][16];
    int b = blockIdx.x;
    int tid = threadIdx.x;        // 512
    int j = tid & 15;
    int kc = tid >> 4;            // 0..31, 16 k each
    const float* h = ws + (size_t)b * NU;   // final h lives in h0 (TT even)
    float acc = 0.0f;
    if (j < OC) {
        for (int u = 0; u < 16; ++u) {
            int k = kc * 16 + u;
            acc += h[k] * Dw[(size_t)k * OC + j];
        }
    }
    red2[kc][j] = acc;
    __syncthreads();
    if (kc == 0 && j < OC) {
        float s = 0.0f;
        #pragma unroll
        for (int u = 0; u < 32; ++u) s += red2[u][j];
        out[(size_t)b * OC + j] = s + Db[j];
    }
}

extern "C" void kernel_launch(void* const* d_in, const int* in_sizes, int n_in,
                              void* d_out, int out_size, void* d_ws, size_t ws_size,
                              hipStream_t stream) {
    const float* x  = (const float*)d_in[0];
    const float* B  = (const float*)d_in[1];
    const float* C  = (const float*)d_in[2];
    const float* Ew = (const float*)d_in[3];
    const float* Eb = (const float*)d_in[4];
    const float* Dw = (const float*)d_in[5];
    const float* Db = (const float*)d_in[6];
    float* ws  = (float*)d_ws;
    float* out = (float*)d_out;

    (void)hipFuncSetAttribute((const void*)scan_kernel,
                              hipFuncAttributeMaxDynamicSharedMemorySize, LDS_BYTES);

    init_kernel<<<256, 256, 0, stream>>>(ws);
    scan_kernel<<<GGRP * CWG, THREADS, LDS_BYTES, stream>>>(x, B, C, Ew, Eb, ws);
    head_kernel<<<BT, THREADS, 0, stream>>>(ws, Dw, Db, out);
}